// Round 3
// baseline (55.766 us; speedup 1.0000x reference)
//
#include <hip/hip_runtime.h>
#include <hip/hip_bf16.h>

// Problem: out[j,k,n] = sum_m pred_coor[j,k,m] * R(r_vector[j])[m,n] + t_vector[j][n]
// Shapes: pred_coor [64,91,3] f32, r_vector [64,3] f32, t_vector [64,3] f32 -> out [64,91,3] f32.
// Tiny (~140 KB total traffic): launch-overhead bound. One thread per (j,k) point.

#define NBATCH 64
#define NPTS   91
#define NPOINTS (NBATCH * NPTS)

__global__ void Align_20237885898851_kernel(const float* __restrict__ coor,
                                            const float* __restrict__ rvec,
                                            const float* __restrict__ tvec,
                                            float* __restrict__ out) {
    int i = blockIdx.x * blockDim.x + threadIdx.x;   // point index in [0, 64*91)
    if (i >= NPOINTS) return;
    int j = i / NPTS;                                 // batch index

    // Quaternion (1,b,c,d)/norm -> rotation matrix
    float b = rvec[j * 3 + 0];
    float c = rvec[j * 3 + 1];
    float d = rvec[j * 3 + 2];
    float inv = 1.0f / sqrtf(1.0f + b * b + c * c + d * d);
    float a = inv;
    b *= inv; c *= inv; d *= inv;

    float aa = a * a, bb = b * b, cc = c * c, dd = d * d;
    float ab = 2.0f * a * b, ac = 2.0f * a * c, ad = 2.0f * a * d;
    float bc = 2.0f * b * c, bd = 2.0f * b * d, cd = 2.0f * c * d;

    // R[m][n] per reference layout
    float R00 = aa + bb - cc - dd;
    float R01 = bc - ad;
    float R02 = bd + ac;
    float R10 = bc + ad;
    float R11 = aa - bb + cc - dd;
    float R12 = cd - ab;
    float R20 = bd - ac;
    float R21 = cd + ab;
    float R22 = aa - bb - cc + dd;

    float x = coor[i * 3 + 0];
    float y = coor[i * 3 + 1];
    float z = coor[i * 3 + 2];

    float t0 = tvec[j * 3 + 0];
    float t1 = tvec[j * 3 + 1];
    float t2 = tvec[j * 3 + 2];

    // out[k,n] = sum_m coor[k,m] * R[m][n] + t[n]
    out[i * 3 + 0] = fmaf(x, R00, fmaf(y, R10, fmaf(z, R20, t0)));
    out[i * 3 + 1] = fmaf(x, R01, fmaf(y, R11, fmaf(z, R21, t1)));
    out[i * 3 + 2] = fmaf(x, R02, fmaf(y, R12, fmaf(z, R22, t2)));
}

extern "C" void kernel_launch(void* const* d_in, const int* in_sizes, int n_in,
                              void* d_out, int out_size, void* d_ws, size_t ws_size,
                              hipStream_t stream) {
    const float* coor = (const float*)d_in[0];
    const float* rvec = (const float*)d_in[1];
    const float* tvec = (const float*)d_in[2];
    float* out = (float*)d_out;

    const int block = 256;
    const int grid = (NPOINTS + block - 1) / block;   // 23 blocks
    Align_20237885898851_kernel<<<grid, block, 0, stream>>>(coor, rvec, tvec, out);
}